// Round 1
// baseline (1553.719 us; speedup 1.0000x reference)
//
#include <hip/hip_runtime.h>
#include <math.h>

#define N_NODES 50000
#define N_EDGES 800000
#define IN_F 64
#define OUT_F 32
#define STEPS 20
#define LR 0.1f
#define SLOPE 0.2f

// ---------------- CSR build ----------------

__global__ void hist_kernel(const int* __restrict__ dst, int* __restrict__ deg) {
    int e = blockIdx.x * blockDim.x + threadIdx.x;
    if (e < N_EDGES) atomicAdd(&deg[dst[e]], 1);
}

// single-block exclusive scan of deg[0..N) -> row_start[0..N]
__global__ void scan_kernel(const int* __restrict__ deg, int* __restrict__ row_start) {
    __shared__ int wsum[16];
    __shared__ int carry_s;
    int tid = threadIdx.x;
    int lane = tid & 63, wid = tid >> 6;
    if (tid == 0) { carry_s = 0; row_start[0] = 0; }
    __syncthreads();
    for (int base = 0; base < N_NODES; base += 1024) {
        int i = base + tid;
        int v = (i < N_NODES) ? deg[i] : 0;
        // wave inclusive scan
        int s = v;
        for (int off = 1; off < 64; off <<= 1) {
            int t = __shfl_up(s, off, 64);
            if (lane >= off) s += t;
        }
        if (lane == 63) wsum[wid] = s;
        __syncthreads();
        if (wid == 0) {
            int ws = (lane < 16) ? wsum[lane] : 0;
            for (int off = 1; off < 16; off <<= 1) {
                int t = __shfl_up(ws, off, 64);
                if (lane >= off) ws += t;
            }
            if (lane < 16) wsum[lane] = ws;
        }
        __syncthreads();
        int wave_off = (wid > 0) ? wsum[wid - 1] : 0;
        int incl = carry_s + wave_off + s;
        if (i < N_NODES) row_start[i + 1] = incl;
        __syncthreads();
        if (tid == 1023) carry_s = incl;
        __syncthreads();
    }
}

__global__ void alpha0_csr_kernel(const int* __restrict__ src, const int* __restrict__ dst,
                                  const int* __restrict__ deg, const int* __restrict__ row_start,
                                  int* __restrict__ cursor, int2* __restrict__ csr,
                                  float* __restrict__ alpha) {
    int e = blockIdx.x * blockDim.x + threadIdx.x;
    if (e < N_EDGES) {
        int d = dst[e];
        alpha[e] = 1.0f / ((float)deg[d] + 1e-8f);
        int p = atomicAdd(&cursor[d], 1);
        csr[row_start[d] + p] = make_int2(src[e], e);
    }
}

// transformed = mu_upper @ W^T  (N x 64) @ (64 x 32)
__global__ void transform_kernel(const float* __restrict__ mu_upper,
                                 const float* __restrict__ W,
                                 float* __restrict__ transformed) {
    int t = blockIdx.x * blockDim.x + threadIdx.x; // t = n*32 + o
    if (t >= N_NODES * OUT_F) return;
    int n = t >> 5, o = t & 31;
    const float4* m4 = (const float4*)(mu_upper + n * IN_F);
    const float4* w4 = (const float4*)(W + o * IN_F);
    float acc = 0.0f;
#pragma unroll
    for (int k = 0; k < 16; k++) {
        float4 a = m4[k], b = w4[k];
        acc += a.x * b.x + a.y * b.y + a.z * b.z + a.w * b.w;
    }
    transformed[t] = acc;
}

// ---------------- main iteration ----------------
// 32 lanes per node: f = feature. Fuses top_down + relu + errors + mu update + score dots.
template <bool FINAL>
__global__ void stepA_kernel(const int* __restrict__ row_start, const int2* __restrict__ csr,
                             const float* __restrict__ alpha, const float* __restrict__ transformed,
                             float* __restrict__ mu, float* __restrict__ errors_out,
                             const float* __restrict__ a_vec,
                             float* __restrict__ s_src, float* __restrict__ s_dst) {
    int n = blockIdx.x * 8 + (threadIdx.x >> 5);
    int f = threadIdx.x & 31;
    if (n >= N_NODES) return;
    int rs = row_start[n], re = row_start[n + 1];
    int cnt = re - rs;
    float agg = 0.0f;
    for (int base = 0; base < cnt; base += 32) {
        int idx = base + f;
        int s = 0; float al = 0.0f;
        if (idx < cnt) {
            int2 se = csr[rs + idx];
            s = se.x;
            al = alpha[se.y];
        }
        int m = cnt - base; if (m > 32) m = 32;
        for (int j = 0; j < m; j++) {
            float alj = __shfl(al, j, 32);
            int   sj  = __shfl(s, j, 32);
            agg = fmaf(alj, transformed[sj * OUT_F + f], agg);
        }
    }
    float mh = fmaxf(agg, 0.0f);
    float muv = mu[n * OUT_F + f];
    float err = muv - mh;
    if (FINAL) {
        errors_out[n * OUT_F + f] = err;
    } else {
        mu[n * OUT_F + f] = fmaf(-LR, err, muv);
        float v1 = err * a_vec[f];
        float v2 = err * a_vec[OUT_F + f];
        for (int off = 16; off >= 1; off >>= 1) {
            v1 += __shfl_xor(v1, off, 32);
            v2 += __shfl_xor(v2, off, 32);
        }
        if (f == 0) { s_src[n] = v1; s_dst[n] = v2; }
    }
}

// one wave per node: leaky-relu scores + segment softmax over incoming edges
__global__ void stepB_kernel(const int* __restrict__ row_start, const int2* __restrict__ csr,
                             const float* __restrict__ s_src, const float* __restrict__ s_dst,
                             float* __restrict__ alpha) {
    int n = blockIdx.x * 4 + (threadIdx.x >> 6);
    int lane = threadIdx.x & 63;
    if (n >= N_NODES) return;
    int rs = row_start[n], re = row_start[n + 1];
    float sd = s_dst[n];
    float m = -INFINITY;
    for (int i = rs + lane; i < re; i += 64) {
        int2 se = csr[i];
        float sc = s_src[se.x] + sd;
        sc = sc > 0.0f ? sc : SLOPE * sc;
        m = fmaxf(m, sc);
    }
    for (int off = 32; off >= 1; off >>= 1) m = fmaxf(m, __shfl_xor(m, off, 64));
    float sum = 0.0f;
    for (int i = rs + lane; i < re; i += 64) {
        int2 se = csr[i];
        float sc = s_src[se.x] + sd;
        sc = sc > 0.0f ? sc : SLOPE * sc;
        sum += expf(sc - m);
    }
    for (int off = 32; off >= 1; off >>= 1) sum += __shfl_xor(sum, off, 64);
    float inv = 1.0f / (sum + 1e-8f);
    for (int i = rs + lane; i < re; i += 64) {
        int2 se = csr[i];
        float sc = s_src[se.x] + sd;
        sc = sc > 0.0f ? sc : SLOPE * sc;
        alpha[se.y] = expf(sc - m) * inv;
    }
}

extern "C" void kernel_launch(void* const* d_in, const int* in_sizes, int n_in,
                              void* d_out, int out_size, void* d_ws, size_t ws_size,
                              hipStream_t stream) {
    const float* mu_upper = (const float*)d_in[0];
    const float* W        = (const float*)d_in[1];
    const float* a_vec    = (const float*)d_in[2];
    const int*   edge_idx = (const int*)d_in[3];
    const int*   src = edge_idx;
    const int*   dst = edge_idx + N_EDGES;

    float* out = (float*)d_out;
    float* mu         = out;                        // N*32
    float* errors_out = out + N_NODES * OUT_F;      // N*32
    float* alpha      = out + 2 * N_NODES * OUT_F;  // E

    char* ws = (char*)d_ws;
    int*   deg       = (int*)(ws + 0);          // 200000 B
    int*   row_start = (int*)(ws + 200000);     // 200004 B
    int*   cursor    = (int*)(ws + 400016);     // 200000 B
    float* s_src     = (float*)(ws + 600016);   // 200000 B
    float* s_dst     = (float*)(ws + 800016);   // 200000 B
    int2*  csr       = (int2*)(ws + 1000016);   // 6400000 B
    float* transformed = (float*)(ws + 7400016);// 6400000 B

    hipMemsetAsync(deg, 0, N_NODES * sizeof(int), stream);
    hipMemsetAsync(cursor, 0, N_NODES * sizeof(int), stream);
    hipMemsetAsync(mu, 0, N_NODES * OUT_F * sizeof(float), stream);

    hist_kernel<<<(N_EDGES + 255) / 256, 256, 0, stream>>>(dst, deg);
    scan_kernel<<<1, 1024, 0, stream>>>(deg, row_start);
    alpha0_csr_kernel<<<(N_EDGES + 255) / 256, 256, 0, stream>>>(src, dst, deg, row_start,
                                                                 cursor, csr, alpha);
    transform_kernel<<<(N_NODES * OUT_F + 255) / 256, 256, 0, stream>>>(mu_upper, W, transformed);

    for (int it = 0; it < STEPS; it++) {
        stepA_kernel<false><<<(N_NODES + 7) / 8, 256, 0, stream>>>(
            row_start, csr, alpha, transformed, mu, errors_out, a_vec, s_src, s_dst);
        stepB_kernel<<<(N_NODES + 3) / 4, 256, 0, stream>>>(row_start, csr, s_src, s_dst, alpha);
    }
    stepA_kernel<true><<<(N_NODES + 7) / 8, 256, 0, stream>>>(
        row_start, csr, alpha, transformed, mu, errors_out, a_vec, s_src, s_dst);
}

// Round 2
// 928.829 us; speedup vs baseline: 1.6728x; 1.6728x over previous
//
#include <hip/hip_runtime.h>
#include <math.h>

#define N_NODES 50000
#define N_EDGES 800000
#define IN_F 64
#define OUT_F 32
#define STEPS 20
#define LR 0.1f
#define SLOPE 0.2f

// ---------------- CSR build ----------------

__global__ void hist_kernel(const int* __restrict__ dst, int* __restrict__ deg) {
    int e = blockIdx.x * blockDim.x + threadIdx.x;
    if (e < N_EDGES) atomicAdd(&deg[dst[e]], 1);
}

// single-block exclusive scan of deg[0..N) -> row_start[0..N]
__global__ void scan_kernel(const int* __restrict__ deg, int* __restrict__ row_start) {
    __shared__ int wsum[16];
    __shared__ int carry_s;
    int tid = threadIdx.x;
    int lane = tid & 63, wid = tid >> 6;
    if (tid == 0) { carry_s = 0; row_start[0] = 0; }
    __syncthreads();
    for (int base = 0; base < N_NODES; base += 1024) {
        int i = base + tid;
        int v = (i < N_NODES) ? deg[i] : 0;
        int s = v;
        for (int off = 1; off < 64; off <<= 1) {
            int t = __shfl_up(s, off, 64);
            if (lane >= off) s += t;
        }
        if (lane == 63) wsum[wid] = s;
        __syncthreads();
        if (wid == 0) {
            int ws = (lane < 16) ? wsum[lane] : 0;
            for (int off = 1; off < 16; off <<= 1) {
                int t = __shfl_up(ws, off, 64);
                if (lane >= off) ws += t;
            }
            if (lane < 16) wsum[lane] = ws;
        }
        __syncthreads();
        int wave_off = (wid > 0) ? wsum[wid - 1] : 0;
        int incl = carry_s + wave_off + s;
        if (i < N_NODES) row_start[i + 1] = incl;
        __syncthreads();
        if (tid == 1023) carry_s = incl;
        __syncthreads();
    }
}

// scatter edges into CSR slots (src, orig_edge_id)
__global__ void csr_build_kernel(const int* __restrict__ src, const int* __restrict__ dst,
                                 const int* __restrict__ row_start,
                                 int* __restrict__ cursor, int2* __restrict__ csr) {
    int e = blockIdx.x * blockDim.x + threadIdx.x;
    if (e < N_EDGES) {
        int d = dst[e];
        int p = atomicAdd(&cursor[d], 1);
        csr[row_start[d] + p] = make_int2(src[e], e);
    }
}

// alpha0 in CSR order: 1/deg per row, coalesced-ish node-parallel
__global__ void alpha_init_kernel(const int* __restrict__ row_start, float* __restrict__ alpha_csr) {
    int n = blockIdx.x * blockDim.x + threadIdx.x;
    if (n >= N_NODES) return;
    int rs = row_start[n], re = row_start[n + 1];
    float v = 1.0f / ((float)(re - rs) + 1e-8f);
    for (int i = rs; i < re; i++) alpha_csr[i] = v;
}

// transformed = mu_upper @ W^T  (N x 64) @ (64 x 32)
__global__ void transform_kernel(const float* __restrict__ mu_upper,
                                 const float* __restrict__ W,
                                 float* __restrict__ transformed) {
    int t = blockIdx.x * blockDim.x + threadIdx.x; // t = n*32 + o
    if (t >= N_NODES * OUT_F) return;
    int n = t >> 5, o = t & 31;
    const float4* m4 = (const float4*)(mu_upper + n * IN_F);
    const float4* w4 = (const float4*)(W + o * IN_F);
    float acc = 0.0f;
#pragma unroll
    for (int k = 0; k < 16; k++) {
        float4 a = m4[k], b = w4[k];
        acc += a.x * b.x + a.y * b.y + a.z * b.z + a.w * b.w;
    }
    transformed[t] = acc;
}

// ---------------- main iteration ----------------
// 32 lanes per node (f = feature). Fuses top_down + relu + errors + mu update + score dots.
// Edge (src, alpha) staged in LDS, broadcast via uniform reads (1 ds_read_b64/edge).
template <bool FINAL>
__global__ void stepA_kernel(const int* __restrict__ row_start, const int2* __restrict__ csr,
                             const float* __restrict__ alpha_csr, const float* __restrict__ transformed,
                             float* __restrict__ mu, float* __restrict__ errors_out,
                             const float* __restrict__ a_vec,
                             float* __restrict__ s_src, float* __restrict__ s_dst) {
    __shared__ int2 s_e[8][32];
    int g = threadIdx.x >> 5, f = threadIdx.x & 31;
    int n = blockIdx.x * 8 + g;
    if (n >= N_NODES) return;
    int rs = row_start[n], re = row_start[n + 1];
    int cnt = re - rs;
    float agg = 0.0f;
    for (int base = 0; base < cnt; base += 32) {
        int k = base + f;
        if (k < cnt) {
            int2 se = csr[rs + k];
            s_e[g][f] = make_int2(se.x << 5, __float_as_int(alpha_csr[rs + k]));
        }
        __threadfence_block();  // order LDS write -> uniform reads (same wave)
        int m = cnt - base; if (m > 32) m = 32;
        for (int j = 0; j < m; j++) {
            int2 p = s_e[g][j];
            agg = fmaf(__int_as_float(p.y), transformed[p.x + f], agg);
        }
        __threadfence_block();
    }
    float mh = fmaxf(agg, 0.0f);
    float muv = mu[n * OUT_F + f];
    float err = muv - mh;
    if (FINAL) {
        errors_out[n * OUT_F + f] = err;
    } else {
        mu[n * OUT_F + f] = fmaf(-LR, err, muv);
        float v1 = err * a_vec[f];
        float v2 = err * a_vec[OUT_F + f];
        for (int off = 16; off >= 1; off >>= 1) {
            v1 += __shfl_xor(v1, off, 32);
            v2 += __shfl_xor(v2, off, 32);
        }
        if (f == 0) { s_src[n] = v1; s_dst[n] = v2; }
    }
}

// 16 lanes per node: leaky-relu scores + segment softmax, alpha written in CSR order.
// Scores cached in registers for the first 2 chunks (covers deg<=32, ~all nodes).
__global__ void stepB_kernel(const int* __restrict__ row_start, const int2* __restrict__ csr,
                             const float* __restrict__ s_src, const float* __restrict__ s_dst,
                             float* __restrict__ alpha_csr) {
    int g = threadIdx.x >> 4;
    int lane = threadIdx.x & 15;
    int n = blockIdx.x * 16 + g;
    if (n >= N_NODES) return;
    int rs = row_start[n], re = row_start[n + 1];
    int cnt = re - rs;
    if (cnt <= 0) return;
    float sd = s_dst[n];
    int nch = (cnt + 15) >> 4;
    float b0 = -INFINITY, b1 = -INFINITY;
    float m = -INFINITY;
    for (int c = 0; c < nch; c++) {
        int idx = rs + (c << 4) + lane;
        float sc = -INFINITY;
        if (idx < re) {
            int s = csr[idx].x;
            sc = s_src[s] + sd;
            sc = sc > 0.0f ? sc : SLOPE * sc;
        }
        if (c == 0) b0 = sc; else if (c == 1) b1 = sc;
        m = fmaxf(m, sc);
    }
    for (int off = 8; off >= 1; off >>= 1) m = fmaxf(m, __shfl_xor(m, off, 16));
    float sum = 0.0f;
    for (int c = 0; c < nch; c++) {
        int idx = rs + (c << 4) + lane;
        float sc;
        if (c == 0) sc = b0;
        else if (c == 1) sc = b1;
        else {
            sc = -INFINITY;
            if (idx < re) {
                int s = csr[idx].x;
                sc = s_src[s] + sd;
                sc = sc > 0.0f ? sc : SLOPE * sc;
            }
        }
        float e = (idx < re) ? expf(sc - m) : 0.0f;
        if (c == 0) b0 = e; else if (c == 1) b1 = e;
        sum += e;
    }
    for (int off = 8; off >= 1; off >>= 1) sum += __shfl_xor(sum, off, 16);
    float inv = 1.0f / (sum + 1e-8f);
    for (int c = 0; c < nch; c++) {
        int idx = rs + (c << 4) + lane;
        float e;
        if (c == 0) e = b0;
        else if (c == 1) e = b1;
        else {
            float sc = -INFINITY;
            if (idx < re) {
                int s = csr[idx].x;
                sc = s_src[s] + sd;
                sc = sc > 0.0f ? sc : SLOPE * sc;
            }
            e = (idx < re) ? expf(sc - m) : 0.0f;
        }
        if (idx < re) alpha_csr[idx] = e * inv;
    }
}

// once at the end: CSR-order alpha -> original edge order
__global__ void scatter_alpha_kernel(const int2* __restrict__ csr,
                                     const float* __restrict__ alpha_csr,
                                     float* __restrict__ alpha_out) {
    int i = blockIdx.x * blockDim.x + threadIdx.x;
    if (i < N_EDGES) alpha_out[csr[i].y] = alpha_csr[i];
}

extern "C" void kernel_launch(void* const* d_in, const int* in_sizes, int n_in,
                              void* d_out, int out_size, void* d_ws, size_t ws_size,
                              hipStream_t stream) {
    const float* mu_upper = (const float*)d_in[0];
    const float* W        = (const float*)d_in[1];
    const float* a_vec    = (const float*)d_in[2];
    const int*   edge_idx = (const int*)d_in[3];
    const int*   src = edge_idx;
    const int*   dst = edge_idx + N_EDGES;

    float* out = (float*)d_out;
    float* mu         = out;                        // N*32
    float* errors_out = out + N_NODES * OUT_F;      // N*32
    float* alpha_out  = out + 2 * N_NODES * OUT_F;  // E

    char* ws = (char*)d_ws;
    int*   deg        = (int*)(ws + 0);             // 200000 B
    int*   row_start  = (int*)(ws + 200000);        // 200004 B
    int*   cursor     = (int*)(ws + 400016);        // 200000 B
    float* s_src      = (float*)(ws + 600016);      // 200000 B
    float* s_dst      = (float*)(ws + 800016);      // 200000 B
    int2*  csr        = (int2*)(ws + 1000016);      // 6400000 B
    float* alpha_csr  = (float*)(ws + 7400016);     // 3200000 B
    float* transformed= (float*)(ws + 10600016);    // 6400000 B  (total ~17.0 MB)

    hipMemsetAsync(deg, 0, N_NODES * sizeof(int), stream);
    hipMemsetAsync(cursor, 0, N_NODES * sizeof(int), stream);
    hipMemsetAsync(mu, 0, N_NODES * OUT_F * sizeof(float), stream);

    hist_kernel<<<(N_EDGES + 255) / 256, 256, 0, stream>>>(dst, deg);
    scan_kernel<<<1, 1024, 0, stream>>>(deg, row_start);
    csr_build_kernel<<<(N_EDGES + 255) / 256, 256, 0, stream>>>(src, dst, row_start, cursor, csr);
    alpha_init_kernel<<<(N_NODES + 255) / 256, 256, 0, stream>>>(row_start, alpha_csr);
    transform_kernel<<<(N_NODES * OUT_F + 255) / 256, 256, 0, stream>>>(mu_upper, W, transformed);

    for (int it = 0; it < STEPS; it++) {
        stepA_kernel<false><<<(N_NODES + 7) / 8, 256, 0, stream>>>(
            row_start, csr, alpha_csr, transformed, mu, errors_out, a_vec, s_src, s_dst);
        stepB_kernel<<<(N_NODES + 15) / 16, 256, 0, stream>>>(row_start, csr, s_src, s_dst, alpha_csr);
    }
    stepA_kernel<true><<<(N_NODES + 7) / 8, 256, 0, stream>>>(
        row_start, csr, alpha_csr, transformed, mu, errors_out, a_vec, s_src, s_dst);
    scatter_alpha_kernel<<<(N_EDGES + 255) / 256, 256, 0, stream>>>(csr, alpha_csr, alpha_out);
}

// Round 3
// 828.420 us; speedup vs baseline: 1.8755x; 1.1212x over previous
//
#include <hip/hip_runtime.h>
#include <math.h>

#define N_NODES 50000
#define N_EDGES 800000
#define IN_F 64
#define OUT_F 32
#define STEPS 20
#define LR 0.1f
#define SLOPE 0.2f

#define SCAN_BLK 256
#define SCAN_NBLK ((N_NODES + SCAN_BLK - 1) / SCAN_BLK)  // 196

// ---------------- CSR build ----------------

__global__ void hist_kernel(const int* __restrict__ dst, int* __restrict__ deg) {
    int e = blockIdx.x * blockDim.x + threadIdx.x;
    if (e < N_EDGES) atomicAdd(&deg[dst[e]], 1);
}

// phase 1: per-block inclusive scan of deg -> row_scan, block totals -> blocksum
__global__ void scan1_kernel(const int* __restrict__ deg, int* __restrict__ row_scan,
                             int* __restrict__ blocksum) {
    __shared__ int wsum[4];
    int tid = threadIdx.x, lane = tid & 63, wid = tid >> 6;
    int i = blockIdx.x * SCAN_BLK + tid;
    int v = (i < N_NODES) ? deg[i] : 0;
    int s = v;
    for (int off = 1; off < 64; off <<= 1) {
        int t = __shfl_up(s, off, 64);
        if (lane >= off) s += t;
    }
    if (lane == 63) wsum[wid] = s;
    __syncthreads();
    if (tid == 0) {
        int a = wsum[0]; wsum[0] = 0;
        int b = wsum[1]; wsum[1] = a; a += b;
        b = wsum[2]; wsum[2] = a; a += b;
        b = wsum[3]; wsum[3] = a; a += b;
        blocksum[blockIdx.x] = a;
    }
    __syncthreads();
    int incl = s + wsum[wid];
    if (i < N_NODES) row_scan[i] = incl;
}

// phase 2: single block, exclusive scan of blocksum in place
__global__ void scan2_kernel(int* __restrict__ blocksum) {
    __shared__ int wsum[4];
    int tid = threadIdx.x, lane = tid & 63, wid = tid >> 6;
    int v = (tid < SCAN_NBLK) ? blocksum[tid] : 0;
    int s = v;
    for (int off = 1; off < 64; off <<= 1) {
        int t = __shfl_up(s, off, 64);
        if (lane >= off) s += t;
    }
    if (lane == 63) wsum[wid] = s;
    __syncthreads();
    if (tid == 0) {
        int a = wsum[0]; wsum[0] = 0;
        int b = wsum[1]; wsum[1] = a; a += b;
        b = wsum[2]; wsum[2] = a; a += b;
        b = wsum[3]; wsum[3] = a; a += b;
    }
    __syncthreads();
    int excl = s - v + wsum[wid];
    if (tid < SCAN_NBLK) blocksum[tid] = excl;
}

// phase 3: add block offsets -> row_start[i+1]; row_start[0]=0
__global__ void scan3_kernel(const int* __restrict__ row_scan, const int* __restrict__ blockoff,
                             int* __restrict__ row_start) {
    int i = blockIdx.x * SCAN_BLK + threadIdx.x;
    if (blockIdx.x == 0 && threadIdx.x == 0) row_start[0] = 0;
    if (i < N_NODES) row_start[i + 1] = row_scan[i] + blockoff[blockIdx.x];
}

// scatter edges into CSR slots: src array + orig edge id array
__global__ void csr_build_kernel(const int* __restrict__ src, const int* __restrict__ dst,
                                 const int* __restrict__ row_start,
                                 int* __restrict__ cursor, int* __restrict__ csr_src,
                                 int* __restrict__ csr_eid) {
    int e = blockIdx.x * blockDim.x + threadIdx.x;
    if (e < N_EDGES) {
        int d = dst[e];
        int p = atomicAdd(&cursor[d], 1) + row_start[d];
        csr_src[p] = src[e];
        csr_eid[p] = e;
    }
}

// alpha0 in CSR order: 1/deg per row
__global__ void alpha_init_kernel(const int* __restrict__ row_start, float* __restrict__ alpha_csr) {
    int n = blockIdx.x * blockDim.x + threadIdx.x;
    if (n >= N_NODES) return;
    int rs = row_start[n], re = row_start[n + 1];
    float v = 1.0f / ((float)(re - rs) + 1e-8f);
    for (int i = rs; i < re; i++) alpha_csr[i] = v;
}

// transformed = mu_upper @ W^T : thread-per-node, W staged in LDS, mu row in regs
__global__ __launch_bounds__(256) void transform_kernel(const float* __restrict__ mu_upper,
                                                        const float* __restrict__ W,
                                                        float* __restrict__ transformed) {
    __shared__ float4 Ws[OUT_F][IN_F / 4];  // 8 KB
    int tid = threadIdx.x;
    for (int t = tid; t < OUT_F * IN_F / 4; t += 256) ((float4*)Ws)[t] = ((const float4*)W)[t];
    __syncthreads();
    int n = blockIdx.x * 256 + tid;
    if (n >= N_NODES) return;
    float4 row[16];
    const float4* m4 = (const float4*)(mu_upper + n * IN_F);
#pragma unroll
    for (int k = 0; k < 16; k++) row[k] = m4[k];
    float4* outp = (float4*)(transformed + n * OUT_F);
#pragma unroll
    for (int oc = 0; oc < OUT_F / 4; oc++) {
        float4 r;
        float* rp = (float*)&r;
#pragma unroll
        for (int oi = 0; oi < 4; oi++) {
            int o = oc * 4 + oi;
            float acc = 0.f;
#pragma unroll
            for (int k = 0; k < 16; k++) {
                float4 w = Ws[o][k];
                acc += row[k].x * w.x + row[k].y * w.y + row[k].z * w.z + row[k].w * w.w;
            }
            rp[oi] = acc;
        }
        outp[oc] = r;
    }
}

// ---------------- main iteration ----------------
// 32 lanes per node (f = feature). Fuses top_down + relu + errors + mu update + score dots.
template <bool FINAL>
__global__ __launch_bounds__(256) void stepA_kernel(
        const int* __restrict__ row_start, const int* __restrict__ csr_src,
        const float* __restrict__ alpha_csr, const float* __restrict__ transformed,
        float* __restrict__ mu, float* __restrict__ errors_out,
        const float* __restrict__ a_vec,
        float* __restrict__ s_src, float* __restrict__ s_dst) {
    __shared__ int2 s_e[8][32];
    int g = threadIdx.x >> 5, f = threadIdx.x & 31;
    int n = blockIdx.x * 8 + g;
    if (n >= N_NODES) return;
    int rs = row_start[n], re = row_start[n + 1];
    int cnt = re - rs;
    float agg = 0.0f;
    for (int base = 0; base < cnt; base += 32) {
        int k = base + f;
        if (k < cnt) {
            s_e[g][f] = make_int2(csr_src[rs + k] << 5, __float_as_int(alpha_csr[rs + k]));
        }
        __threadfence_block();  // order LDS write -> uniform reads (same wave)
        int m = cnt - base; if (m > 32) m = 32;
        int j = 0;
        for (; j + 4 <= m; j += 4) {
            int2 p0 = s_e[g][j + 0];
            int2 p1 = s_e[g][j + 1];
            int2 p2 = s_e[g][j + 2];
            int2 p3 = s_e[g][j + 3];
            float t0 = transformed[p0.x + f];
            float t1 = transformed[p1.x + f];
            float t2 = transformed[p2.x + f];
            float t3 = transformed[p3.x + f];
            agg = fmaf(__int_as_float(p0.y), t0, agg);
            agg = fmaf(__int_as_float(p1.y), t1, agg);
            agg = fmaf(__int_as_float(p2.y), t2, agg);
            agg = fmaf(__int_as_float(p3.y), t3, agg);
        }
        for (; j < m; j++) {
            int2 p = s_e[g][j];
            agg = fmaf(__int_as_float(p.y), transformed[p.x + f], agg);
        }
        __threadfence_block();
    }
    float mh = fmaxf(agg, 0.0f);
    float muv = mu[n * OUT_F + f];
    float err = muv - mh;
    if (FINAL) {
        errors_out[n * OUT_F + f] = err;
    } else {
        mu[n * OUT_F + f] = fmaf(-LR, err, muv);
        float v1 = err * a_vec[f];
        float v2 = err * a_vec[OUT_F + f];
        for (int off = 16; off >= 1; off >>= 1) {
            v1 += __shfl_xor(v1, off, 32);
            v2 += __shfl_xor(v2, off, 32);
        }
        if (f == 0) { s_src[n] = v1; s_dst[n] = v2; }
    }
}

// 16 lanes per node: leaky-relu scores + segment softmax, alpha in CSR order.
__global__ __launch_bounds__(256) void stepB_kernel(
        const int* __restrict__ row_start, const int* __restrict__ csr_src,
        const float* __restrict__ s_src, const float* __restrict__ s_dst,
        float* __restrict__ alpha_csr) {
    int g = threadIdx.x >> 4;
    int lane = threadIdx.x & 15;
    int n = blockIdx.x * 16 + g;
    if (n >= N_NODES) return;
    int rs = row_start[n], re = row_start[n + 1];
    int cnt = re - rs;
    if (cnt <= 0) return;
    float sd = s_dst[n];
    int nch = (cnt + 15) >> 4;
    float b0 = -INFINITY, b1 = -INFINITY;
    float m = -INFINITY;
    for (int c = 0; c < nch; c++) {
        int idx = rs + (c << 4) + lane;
        float sc = -INFINITY;
        if (idx < re) {
            float v = s_src[csr_src[idx]] + sd;
            sc = v > 0.0f ? v : SLOPE * v;
        }
        if (c == 0) b0 = sc; else if (c == 1) b1 = sc;
        m = fmaxf(m, sc);
    }
    for (int off = 8; off >= 1; off >>= 1) m = fmaxf(m, __shfl_xor(m, off, 16));
    float sum = 0.0f;
    for (int c = 0; c < nch; c++) {
        int idx = rs + (c << 4) + lane;
        float sc;
        if (c == 0) sc = b0;
        else if (c == 1) sc = b1;
        else {
            sc = -INFINITY;
            if (idx < re) {
                float v = s_src[csr_src[idx]] + sd;
                sc = v > 0.0f ? v : SLOPE * v;
            }
        }
        float e = (idx < re) ? __expf(sc - m) : 0.0f;
        if (c == 0) b0 = e; else if (c == 1) b1 = e;
        sum += e;
    }
    for (int off = 8; off >= 1; off >>= 1) sum += __shfl_xor(sum, off, 16);
    float inv = 1.0f / (sum + 1e-8f);
    for (int c = 0; c < nch; c++) {
        int idx = rs + (c << 4) + lane;
        float e;
        if (c == 0) e = b0;
        else if (c == 1) e = b1;
        else {
            float sc = -INFINITY;
            if (idx < re) {
                float v = s_src[csr_src[idx]] + sd;
                sc = v > 0.0f ? v : SLOPE * v;
            }
            e = (idx < re) ? __expf(sc - m) : 0.0f;
        }
        if (idx < re) alpha_csr[idx] = e * inv;
    }
}

// once at the end: CSR-order alpha -> original edge order
__global__ void scatter_alpha_kernel(const int* __restrict__ csr_eid,
                                     const float* __restrict__ alpha_csr,
                                     float* __restrict__ alpha_out) {
    int i = blockIdx.x * blockDim.x + threadIdx.x;
    if (i < N_EDGES) alpha_out[csr_eid[i]] = alpha_csr[i];
}

extern "C" void kernel_launch(void* const* d_in, const int* in_sizes, int n_in,
                              void* d_out, int out_size, void* d_ws, size_t ws_size,
                              hipStream_t stream) {
    const float* mu_upper = (const float*)d_in[0];
    const float* W        = (const float*)d_in[1];
    const float* a_vec    = (const float*)d_in[2];
    const int*   edge_idx = (const int*)d_in[3];
    const int*   src = edge_idx;
    const int*   dst = edge_idx + N_EDGES;

    float* out = (float*)d_out;
    float* mu         = out;                        // N*32
    float* errors_out = out + N_NODES * OUT_F;      // N*32
    float* alpha_out  = out + 2 * N_NODES * OUT_F;  // E

    char* ws = (char*)d_ws;
    int*   deg        = (int*)(ws + 0);             // 200000
    int*   row_scan   = (int*)(ws + 200000);        // 200000
    int*   row_start  = (int*)(ws + 400000);        // 200004
    int*   blocksum   = (int*)(ws + 600016);        // 1024
    int*   cursor     = (int*)(ws + 601040);        // 200000
    float* s_src      = (float*)(ws + 801040);      // 200000
    float* s_dst      = (float*)(ws + 1001040);     // 200000
    int*   csr_src    = (int*)(ws + 1201040);       // 3200000
    int*   csr_eid    = (int*)(ws + 4401040);       // 3200000
    float* alpha_csr  = (float*)(ws + 7601040);     // 3200000
    float* transformed= (float*)(ws + 10801040);    // 6400000  (end ~17.2 MB)

    hipMemsetAsync(deg, 0, N_NODES * sizeof(int), stream);
    hipMemsetAsync(cursor, 0, N_NODES * sizeof(int), stream);
    hipMemsetAsync(mu, 0, N_NODES * OUT_F * sizeof(float), stream);

    hist_kernel<<<(N_EDGES + 255) / 256, 256, 0, stream>>>(dst, deg);
    scan1_kernel<<<SCAN_NBLK, SCAN_BLK, 0, stream>>>(deg, row_scan, blocksum);
    scan2_kernel<<<1, 256, 0, stream>>>(blocksum);
    scan3_kernel<<<SCAN_NBLK, SCAN_BLK, 0, stream>>>(row_scan, blocksum, row_start);
    csr_build_kernel<<<(N_EDGES + 255) / 256, 256, 0, stream>>>(src, dst, row_start, cursor,
                                                                csr_src, csr_eid);
    alpha_init_kernel<<<(N_NODES + 255) / 256, 256, 0, stream>>>(row_start, alpha_csr);
    transform_kernel<<<(N_NODES + 255) / 256, 256, 0, stream>>>(mu_upper, W, transformed);

    for (int it = 0; it < STEPS; it++) {
        stepA_kernel<false><<<(N_NODES + 7) / 8, 256, 0, stream>>>(
            row_start, csr_src, alpha_csr, transformed, mu, errors_out, a_vec, s_src, s_dst);
        stepB_kernel<<<(N_NODES + 15) / 16, 256, 0, stream>>>(row_start, csr_src, s_src, s_dst,
                                                              alpha_csr);
    }
    stepA_kernel<true><<<(N_NODES + 7) / 8, 256, 0, stream>>>(
        row_start, csr_src, alpha_csr, transformed, mu, errors_out, a_vec, s_src, s_dst);
    scatter_alpha_kernel<<<(N_EDGES + 255) / 256, 256, 0, stream>>>(csr_eid, alpha_csr, alpha_out);
}